// Round 13
// baseline (624.194 us; speedup 1.0000x reference)
//
#include <hip/hip_runtime.h>

// ---------------------------------------------------------------------------
// snnBlock, round 13: r11 core (rotation & setprio reverted — both regressed)
// with LDS stride 40 -> 32 u16 (64B, bank-uniform 8/bank proven) so alds
// drops 43.2 -> 34.6 KB => 4 blocks/CU (was 3). Single lever vs r11.
// ---------------------------------------------------------------------------

typedef unsigned short u16;
typedef __attribute__((ext_vector_type(8))) __bf16 bf16x8;
typedef __attribute__((ext_vector_type(4))) float   f32x4;

#define T_ 4
#define B_ 8
#define CIN 64
#define COUT 128
#define H_ 48
#define W_ 48
#define HW 2304
#define NPIX 18432
#define KTOT 1728
#define WTPL 884736            // elements per weight plane
#define M2PL 2359296           // u16 per m2 plane [B][8][HW][16]
#define APL  5760              // u16 per alds plane (180 px * 32)

// ---- workspace layout (32-bit words) ----
#define OFF_SYNE  0
#define OFF_SYNI  1179648
#define OFF_SPK1H 2359296      // bf16 [B][4][HW][16]
#define OFF_CNT   2949120      // int [T][128]
#define ZERO_W    2949632
#define OFF_SYN2  2949632      // f32 fragment layout (2359296 words)
#define OFF_SPK2H 5308928      // bf16 [B][8][HW][16]
#define OFF_M2H0  6488576      // 3 contiguous planes, buffer 0
#define OFF_M2H1  10027520     // 3 contiguous planes, buffer 1
#define OFF_WT    13566464     // bf16 [3][884736]
#define OFF_U     14893568

static __device__ __forceinline__ u16 bfbits(float f) {
    __bf16 h = (__bf16)f; u16 u; __builtin_memcpy(&u, &h, 2); return u;
}
static __device__ __forceinline__ float bff(u16 u) {
    __bf16 h; __builtin_memcpy(&h, &u, 2); return (float)h;
}
static __device__ __forceinline__ f32x4 MFMA(bf16x8 a, bf16x8 b, f32x4 c) {
    return __builtin_amdgcn_mfma_f32_16x16x32_bf16(a, b, c, 0, 0, 0);
}

// ---------------------------------------------------------------------------
__global__ __launch_bounds__(256) void zero_ws_kernel(float* __restrict__ p, int n) {
    int i = blockIdx.x * 256 + threadIdx.x;
    if (i < n) p[i] = 0.0f;
}

// ---------------------------------------------------------------------------
// Weight transform (r7-verified, unchanged).
__global__ __launch_bounds__(256) void wt_transform_kernel(
        const float* __restrict__ w, u16* __restrict__ wt) {
    int id = blockIdx.x * 256 + threadIdx.x;      // 110592
    int lane = id & 63;
    int rest = id >> 6;
    int tap = rest % 9;
    int rest2 = rest / 9;
    int ck = rest2 % 6, nt = rest2 / 6;
    int gate = nt & 3, cg = nt >> 2;
    int coutsub = lane & 15, kgl = lane >> 4;
    int oc = gate * COUT + cg * 16 + coutsub;
    int kh = tap / 3, kw = tap - kh * 3;
    size_t dst = ((size_t)(nt * 6 + ck) * 9 + tap) * 512 + lane * 8;
#pragma unroll
    for (int j = 0; j < 8; ++j) {
        int ch = ck * 32 + kgl * 8 + j;
        float wv = w[((oc * 192 + ch) * 3 + kh) * 3 + kw];
        float hh = (float)(__bf16)wv;
        float r1 = wv - hh;
        float ll = (float)(__bf16)r1;
        float r2 = r1 - ll;
        wt[dst + j]            = bfbits(hh);
        wt[WTPL + dst + j]     = bfbits(ll);
        wt[2 * WTPL + dst + j] = bfbits(r2);
    }
}

// ---------------------------------------------------------------------------
// Alpha neuron; spk1 [B][4][HW][16] (16-channel-blocked).
__global__ __launch_bounds__(256) void alpha_step_kernel(
        const float4* __restrict__ x_t,
        const float* __restrict__ p_alpha, const float* __restrict__ p_beta,
        const float* __restrict__ p_th1,
        float4* __restrict__ syn_e, float4* __restrict__ syn_i,
        u16* __restrict__ spk1h) {
#pragma clang fp contract(off)
    int q = blockIdx.x * 256 + threadIdx.x;       // 294912 quads
    float a = fminf(fmaxf(p_alpha[0], 1e-6f), 1.0f - 1e-6f);
    float b = fminf(fmaxf(p_beta[0],  1e-6f), 1.0f - 1e-6f);
    float la = logf(a), lb = logf(b);
    float tau = la / (lb - la);
    float th1 = p_th1[0];

    int bc = q / 576;                              // b*64 + c
    int hw0 = (q - bc * 576) * 4;
    int bb = bc >> 6, c = bc & 63;
    u16* sp = spk1h + ((size_t)(bb * 4 + (c >> 4)) * HW + hw0) * 16 + (c & 15);

    float4 xv = x_t[q], e4 = syn_e[q], i4 = syn_i[q];
    float pr0 = bff(sp[0]), pr1 = bff(sp[16]), pr2 = bff(sp[32]), pr3 = bff(sp[48]);
    float e, ii, m1;
    u16 s0, s1, s2, s3;
    e = a * e4.x + xv.x; ii = b * i4.x - xv.x; m1 = tau * (e + ii) - pr0 * th1;
    e4.x = e; i4.x = ii; s0 = (m1 - th1) > 0.0f ? 0x3F80u : 0u;
    e = a * e4.y + xv.y; ii = b * i4.y - xv.y; m1 = tau * (e + ii) - pr1 * th1;
    e4.y = e; i4.y = ii; s1 = (m1 - th1) > 0.0f ? 0x3F80u : 0u;
    e = a * e4.z + xv.z; ii = b * i4.z - xv.z; m1 = tau * (e + ii) - pr2 * th1;
    e4.z = e; i4.z = ii; s2 = (m1 - th1) > 0.0f ? 0x3F80u : 0u;
    e = a * e4.w + xv.w; ii = b * i4.w - xv.w; m1 = tau * (e + ii) - pr3 * th1;
    e4.w = e; i4.w = ii; s3 = (m1 - th1) > 0.0f ? 0x3F80u : 0u;
    syn_e[q] = e4; syn_i[q] = i4;
    sp[0] = s0; sp[16] = s1; sp[32] = s2; sp[48] = s3;
}

// ---------------------------------------------------------------------------
__global__ void t0_u_kernel(const float* __restrict__ b_conv, float* __restrict__ u) {
#pragma clang fp contract(off)
    int c = threadIdx.x;                           // 128
    float gi = b_conv[c], gf = b_conv[COUT + c];
    float gg = b_conv[2 * COUT + c], go = b_conv[3 * COUT + c];
    float si = 1.0f / (1.0f + expf(-gi));
    float sf = 1.0f / (1.0f + expf(-gf));
    float so = 1.0f / (1.0f + expf(-go));
    float tg = tanhf(gg);
    float s2 = sf * 0.0f + si * tg;
    float m2 = so * tanhf(s2);
    u[c] = s2;
    u16* uh = (u16*)(u + 128);
    float hh = (float)(__bf16)m2;
    float r1 = m2 - hh;
    float ll = (float)(__bf16)r1;
    float r2 = r1 - ll;
    uh[c] = bfbits(hh); uh[128 + c] = bfbits(ll); uh[256 + c] = bfbits(r2);
}

__global__ __launch_bounds__(256) void t0_fillA_kernel(
        const float* __restrict__ u, const float* __restrict__ bnb,
        float4* __restrict__ out0) {
    int i = blockIdx.x * 256 + threadIdx.x;        // 589824 quads
    int c = ((i * 4) / HW) % COUT;
    float bb = bnb[c];
    out0[i] = make_float4(bb, bb, bb, bb);
}

// t=0 fill B: m2 planes buffer 0 (16-ch-blocked) + syn2 (fragment layout).
__global__ __launch_bounds__(256) void t0_fillB_kernel(
        const float* __restrict__ u,
        u16* __restrict__ m2, float4* __restrict__ syn2) {
    int i = blockIdx.x * 256 + threadIdx.x;        // 589824
    const u16* uh = (const u16*)(u + 128);
    int pxg = i >> 2;
    int cg = (pxg / HW) & 7;
    int c0 = cg * 16 + (i & 3) * 4;
    *(uint2*)(m2 + (size_t)i * 4)             = *(const uint2*)(uh + c0);
    *(uint2*)(m2 + M2PL + (size_t)i * 4)      = *(const uint2*)(uh + 128 + c0);
    *(uint2*)(m2 + 2 * M2PL + (size_t)i * 4)  = *(const uint2*)(uh + 256 + c0);
    int csy = ((i >> 9) & 7) * 16 + (i & 15);
    float s2 = u[csy];
    syn2[i] = make_float4(s2, s2, s2, s2);
}

// ---------------------------------------------------------------------------
// MFMA conv + fused LSTM. Block: 4 waves, wave = 1 nt, M=128 px (8x16 tile).
// Grid 1152: bx = ntq*144 + mt*8 + b -> XCD = b.
#define LDSROW(P, r, kw) (*(const bf16x8*)&alds[P][(((r) * 18) + m16 + (kw)) * 32 + kg * 8])
__global__ __launch_bounds__(256, 4) void conv_lstm_fused(
        const u16* __restrict__ spk1h,
        const u16* __restrict__ m2rd,      // base of 3 contiguous planes
        const u16* __restrict__ wt,
        const float* __restrict__ bias, const float* __restrict__ p_th2,
        float* __restrict__ syn2,
        u16* __restrict__ m2wr,            // base of 3 contiguous planes
        u16* __restrict__ spk2h, int* __restrict__ cnt) {
    __shared__ __align__(16) u16 alds[3][APL];     // 34.6 KB; reused as f32 glds

    const int bx  = blockIdx.x;
    const int ntq = bx / 144;
    const int rm  = bx - ntq * 144;
    const int mt  = rm >> 3;
    const int b   = rm & 7;
    const int mt3 = mt / 3;
    const int h0 = mt3 * 8, w0 = (mt - mt3 * 3) * 16;

    const int tid = threadIdx.x;
    const int wn  = tid >> 6;
    const int lane = tid & 63;
    const int m16 = lane & 15;
    const int kg  = lane >> 4;
    const int nt = ntq * 4 + wn;

    f32x4 acc[8];
#pragma unroll
    for (int mf = 0; mf < 8; ++mf) acc[mf] = (f32x4){0.f, 0.f, 0.f, 0.f};

    // ---- hoisted mem2 staging indices ----
    int ldsM[9], srcM[9];
#pragma unroll
    for (int j = 0; j < 9; ++j) {
        int i = tid + j * 256;
        int pl = i / 720;
        int r = i - pl * 720;
        int px = r >> 2, qt = r & 3;
        int rr = px / 18, cc2 = px - rr * 18;
        int gh = h0 - 1 + rr, gw = w0 - 1 + cc2;
        ldsM[j] = (i < 2160) ? (pl * APL + px * 32 + qt * 8) : -1;
        bool ok = (i < 2160) && ((unsigned)gh < 48u) && ((unsigned)gw < 48u);
        srcM[j] = ok ? (pl * M2PL + ((b * 8 + (qt >> 1)) * HW + gh * 48 + gw) * 16
                        + (qt & 1) * 8) : -1;
    }

    // ---- binary staging: ck 0,1 -> planes 0,1 (one shot) ----
    {
        uint4 stB[6]; int ldsB[6];
#pragma unroll
        for (int j = 0; j < 6; ++j) {
            int i = tid + j * 256;
            int ckb = i / 720;
            int r = i - ckb * 720;
            int px = r >> 2, qt = r & 3;
            int rr = px / 18, cc2 = px - rr * 18;
            int gh = h0 - 1 + rr, gw = w0 - 1 + cc2;
            ldsB[j] = (i < 1440) ? (ckb * APL + px * 32 + qt * 8) : -1;
            uint4 v = make_uint4(0u, 0u, 0u, 0u);
            if (i < 1440 && (unsigned)gh < 48u && (unsigned)gw < 48u)
                v = *(const uint4*)(spk1h
                    + ((size_t)(b * 4 + ckb * 2 + (qt >> 1)) * HW + gh * 48 + gw) * 16
                    + (qt & 1) * 8);
            stB[j] = v;
        }
#pragma unroll
        for (int j = 0; j < 6; ++j)
            if (ldsB[j] >= 0) *(uint4*)&alds[0][ldsB[j]] = stB[j];
    }
    __syncthreads();

    uint4 stM[9];
#define LOADM(ck_)                                                           \
    {                                                                        \
        const int add = ((ck_) - 2) * (2 * HW * 16);                         \
        _Pragma("unroll")                                                    \
        for (int j = 0; j < 9; ++j) {                                        \
            uint4 v = make_uint4(0u, 0u, 0u, 0u);                            \
            if (srcM[j] >= 0) v = *(const uint4*)(m2rd + srcM[j] + add);     \
            stM[j] = v;                                                      \
        }                                                                    \
    }
#define WRITEM                                                               \
    {                                                                        \
        _Pragma("unroll")                                                    \
        for (int j = 0; j < 9; ++j)                                          \
            if (ldsM[j] >= 0) *(uint4*)&alds[0][ldsM[j]] = stM[j];           \
    }

    LOADM(2);                                      // in flight under binary compute

    // ---- binary compute (3-term), planes 0,1 ----
    for (int ckb = 0; ckb < 2; ++ckb) {
#pragma unroll
        for (int kw = 0; kw < 3; ++kw) {
            bf16x8 B0[3], B1[3], B2[3];
#pragma unroll
            for (int kh = 0; kh < 3; ++kh) {
                const size_t bo = ((size_t)(nt * 6 + ckb) * 9 + kh * 3 + kw) * 512 + lane * 8;
                B0[kh] = *(const bf16x8*)(wt + bo);
                B1[kh] = *(const bf16x8*)(wt + WTPL + bo);
                B2[kh] = *(const bf16x8*)(wt + 2 * WTPL + bo);
            }
            bf16x8 aw[3];
            aw[0] = LDSROW(ckb, 0, kw);
            aw[1] = LDSROW(ckb, 1, kw);
#pragma unroll
            for (int mf = 0; mf < 8; ++mf) {
                aw[(mf + 2) % 3] = LDSROW(ckb, mf + 2, kw);
#pragma unroll
                for (int kh = 0; kh < 3; ++kh) {
                    const bf16x8 A = aw[(mf + kh) % 3];
                    acc[mf] = MFMA(A, B0[kh], acc[mf]);
                    acc[mf] = MFMA(A, B1[kh], acc[mf]);
                    acc[mf] = MFMA(A, B2[kh], acc[mf]);
                }
            }
        }
    }

    // ---- mem2 chunks (7-term), pipelined staging ----
    for (int ck = 2; ck < 6; ++ck) {
        __syncthreads();
        WRITEM;
        __syncthreads();
        if (ck < 5) LOADM(ck + 1);
#pragma unroll
        for (int kw = 0; kw < 3; ++kw) {
            bf16x8 B0[3], B1[3], B2[3];
#pragma unroll
            for (int kh = 0; kh < 3; ++kh) {
                const size_t bo = ((size_t)(nt * 6 + ck) * 9 + kh * 3 + kw) * 512 + lane * 8;
                B0[kh] = *(const bf16x8*)(wt + bo);
                B1[kh] = *(const bf16x8*)(wt + WTPL + bo);
                B2[kh] = *(const bf16x8*)(wt + 2 * WTPL + bo);
            }
            bf16x8 a0[3], a1[3], a2[3];
            a0[0] = LDSROW(0, 0, kw); a0[1] = LDSROW(0, 1, kw);
            a1[0] = LDSROW(1, 0, kw); a1[1] = LDSROW(1, 1, kw);
            a2[0] = LDSROW(2, 0, kw); a2[1] = LDSROW(2, 1, kw);
#pragma unroll
            for (int mf = 0; mf < 8; ++mf) {
                const int sn = (mf + 2) % 3;
                a0[sn] = LDSROW(0, mf + 2, kw);
                a1[sn] = LDSROW(1, mf + 2, kw);
                a2[sn] = LDSROW(2, mf + 2, kw);
#pragma unroll
                for (int kh = 0; kh < 3; ++kh) {
                    const int s = (mf + kh) % 3;
                    acc[mf] = MFMA(a0[s], B0[kh], acc[mf]);
                    acc[mf] = MFMA(a0[s], B1[kh], acc[mf]);
                    acc[mf] = MFMA(a0[s], B2[kh], acc[mf]);
                    acc[mf] = MFMA(a1[s], B0[kh], acc[mf]);
                    acc[mf] = MFMA(a1[s], B1[kh], acc[mf]);
                    acc[mf] = MFMA(a2[s], B0[kh], acc[mf]);
                    acc[mf] = MFMA(a2[s], B1[kh], acc[mf]);
                }
            }
        }
    }

    // ---- gate exchange through LDS, then fused LSTM ----
    __syncthreads();
    {
        float* glds = (float*)alds;
#pragma unroll
        for (int mf = 0; mf < 8; ++mf)
            *(f32x4*)(glds + (wn * 8 + mf) * 256 + lane * 4) = acc[mf];
    }
    __syncthreads();
    {
#pragma clang fp contract(off)
        const float* glds = (const float*)alds;
        const int c = ntq * 16 + m16;
        const float th2 = p_th2[0];
        const float b0 = bias[c],       b1 = bias[128 + c];
        const float b2 = bias[256 + c], b3 = bias[384 + c];
        int sc = 0;
#pragma unroll
        for (int q = 0; q < 2; ++q) {
            const int mfq = wn * 2 + q;
            const f32x4 vI = *(const f32x4*)(glds + (0 * 8 + mfq) * 256 + lane * 4);
            const f32x4 vF = *(const f32x4*)(glds + (1 * 8 + mfq) * 256 + lane * 4);
            const f32x4 vG = *(const f32x4*)(glds + (2 * 8 + mfq) * 256 + lane * 4);
            const f32x4 vO = *(const f32x4*)(glds + (3 * 8 + mfq) * 256 + lane * 4);
            const size_t sidx = ((size_t)(((b * 18 + mt) * 8 + ntq) * 8 + mfq) * 64 + lane) * 4;
            const f32x4 s2v = *(const f32x4*)(syn2 + sidx);
            const int h = h0 + mfq;
            const size_t pixb = ((size_t)(b * 8 + ntq) * HW + h * 48 + w0 + kg * 4) * 16 + m16;
            f32x4 s2o;
#pragma unroll
            for (int j = 0; j < 4; ++j) {
                float gi = vI[j] + b0, gf = vF[j] + b1;
                float gg = vG[j] + b2, go = vO[j] + b3;
                float si = 1.0f / (1.0f + expf(-gi));
                float sf = 1.0f / (1.0f + expf(-gf));
                float so = 1.0f / (1.0f + expf(-go));
                float tg = tanhf(gg);
                float s2 = sf * s2v[j] + si * tg;
                float m2 = so * tanhf(s2);
                s2o[j] = s2;
                float hh = (float)(__bf16)m2;
                float r1 = m2 - hh;
                float ll = (float)(__bf16)r1;
                float r2 = r1 - ll;
                const size_t pix = pixb + (size_t)j * 16;
                m2wr[pix]             = bfbits(hh);
                m2wr[M2PL + pix]      = bfbits(ll);
                m2wr[2 * M2PL + pix]  = bfbits(r2);
                bool sp = (m2 - th2) > 0.0f;
                spk2h[pix] = sp ? 0x3F80u : 0u;
                sc += sp ? 1 : 0;
            }
            *(f32x4*)(syn2 + sidx) = s2o;
        }
        sc += __shfl_xor(sc, 16);
        sc += __shfl_xor(sc, 32);
        if (lane < 16) atomicAdd(&cnt[ntq * 16 + lane], sc);
    }
#undef LOADM
#undef WRITEM
}

// ---------------------------------------------------------------------------
// BN of binary spikes; spk2h is [B][8][HW][16].
__global__ __launch_bounds__(256) void bn_step_kernel(
        const u16* __restrict__ spk2h, const int* __restrict__ cnt,
        const float* __restrict__ gamma, const float* __restrict__ bnb,
        float4* __restrict__ out) {
#pragma clang fp contract(off)
    int i = blockIdx.x * 256 + threadIdx.x;        // 589824 quads (ch-major out)
    int e = i * 4;
    int tmp = e / HW;                               // b*128 + c
    int bb = tmp >> 7, c = tmp & 127;
    int hw0 = e - tmp * HW;
    const u16* sp = spk2h + ((size_t)(bb * 8 + (c >> 4)) * HW + hw0) * 16 + (c & 15);
    float mu  = (float)cnt[c] / (float)NPIX;
    float var = mu - mu * mu;
    float rs  = rsqrtf(var + 1e-5f);
    float g = gamma[c], bv = bnb[c];
    float s0 = bff(sp[0]), s1 = bff(sp[16]), s2 = bff(sp[32]), s3 = bff(sp[48]);
    out[i] = make_float4(g * (s0 - mu) * rs + bv, g * (s1 - mu) * rs + bv,
                         g * (s2 - mu) * rs + bv, g * (s3 - mu) * rs + bv);
}

// ---------------------------------------------------------------------------
extern "C" void kernel_launch(void* const* d_in, const int* in_sizes, int n_in,
                              void* d_out, int out_size, void* d_ws, size_t ws_size,
                              hipStream_t stream) {
    const float* x       = (const float*)d_in[0];
    const float* p_alpha = (const float*)d_in[1];
    const float* p_beta  = (const float*)d_in[2];
    const float* p_th1   = (const float*)d_in[3];
    const float* p_th2   = (const float*)d_in[4];
    const float* w_conv  = (const float*)d_in[5];
    const float* b_conv  = (const float*)d_in[6];
    const float* gamma   = (const float*)d_in[7];
    const float* bn_beta = (const float*)d_in[8];
    float* out = (float*)d_out;

    float* wsf   = (float*)d_ws;
    float* syn_e = wsf + OFF_SYNE;
    float* syn_i = wsf + OFF_SYNI;
    u16*   spk1h = (u16*)(wsf + OFF_SPK1H);
    int*   cnt   = (int*)(wsf + OFF_CNT);
    float* syn2  = wsf + OFF_SYN2;
    u16*   spk2h = (u16*)(wsf + OFF_SPK2H);
    u16*   m2buf[2] = {(u16*)(wsf + OFF_M2H0), (u16*)(wsf + OFF_M2H1)};
    u16*   wt    = (u16*)(wsf + OFF_WT);
    float* u     = wsf + OFF_U;

    zero_ws_kernel<<<ZERO_W / 256, 256, 0, stream>>>(wsf, ZERO_W);
    wt_transform_kernel<<<432, 256, 0, stream>>>(w_conv, wt);

    // ---- t = 0 (algebraic) ----
    alpha_step_kernel<<<1152, 256, 0, stream>>>(
        (const float4*)x, p_alpha, p_beta, p_th1,
        (float4*)syn_e, (float4*)syn_i, spk1h);
    t0_u_kernel<<<1, COUT, 0, stream>>>(b_conv, u);
    t0_fillA_kernel<<<2304, 256, 0, stream>>>(u, bn_beta, (float4*)out);
    t0_fillB_kernel<<<2304, 256, 0, stream>>>(u, m2buf[0], (float4*)syn2);

    // ---- t = 1..3 ----
    for (int t = 1; t < T_; ++t) {
        const int rd = (t - 1) & 1, wr = t & 1;
        alpha_step_kernel<<<1152, 256, 0, stream>>>(
            (const float4*)(x + (size_t)t * 1179648), p_alpha, p_beta, p_th1,
            (float4*)syn_e, (float4*)syn_i, spk1h);
        conv_lstm_fused<<<1152, 256, 0, stream>>>(
            spk1h, m2buf[rd], wt, b_conv, p_th2,
            syn2, m2buf[wr], spk2h, cnt + t * COUT);
        bn_step_kernel<<<2304, 256, 0, stream>>>(
            spk2h, cnt + t * COUT, gamma, bn_beta,
            (float4*)(out + (size_t)t * 2359296));
    }
}

// Round 14
// 555.055 us; speedup vs baseline: 1.1246x; 1.1246x over previous
//
#include <hip/hip_runtime.h>

// ---------------------------------------------------------------------------
// snnBlock, round 14: r13 kernel with __launch_bounds__(256,3) — the (256,4)
// bound forced VGPR 84->64 and spilled to scratch (WRITE 46->182 MB, FETCH
// 55->147 MB, MfmaUtil 53->34). 84 VGPR already permits 4 waves/SIMD (m69
// steps at 64/128), and LDS 34.6 KB x4 = 138.4 <= 160 KB => 4 blocks/CU
// without any register squeeze.
// ---------------------------------------------------------------------------

typedef unsigned short u16;
typedef __attribute__((ext_vector_type(8))) __bf16 bf16x8;
typedef __attribute__((ext_vector_type(4))) float   f32x4;

#define T_ 4
#define B_ 8
#define CIN 64
#define COUT 128
#define H_ 48
#define W_ 48
#define HW 2304
#define NPIX 18432
#define KTOT 1728
#define WTPL 884736            // elements per weight plane
#define M2PL 2359296           // u16 per m2 plane [B][8][HW][16]
#define APL  5760              // u16 per alds plane (180 px * 32)

// ---- workspace layout (32-bit words) ----
#define OFF_SYNE  0
#define OFF_SYNI  1179648
#define OFF_SPK1H 2359296      // bf16 [B][4][HW][16]
#define OFF_CNT   2949120      // int [T][128]
#define ZERO_W    2949632
#define OFF_SYN2  2949632      // f32 fragment layout (2359296 words)
#define OFF_SPK2H 5308928      // bf16 [B][8][HW][16]
#define OFF_M2H0  6488576      // 3 contiguous planes, buffer 0
#define OFF_M2H1  10027520     // 3 contiguous planes, buffer 1
#define OFF_WT    13566464     // bf16 [3][884736]
#define OFF_U     14893568

static __device__ __forceinline__ u16 bfbits(float f) {
    __bf16 h = (__bf16)f; u16 u; __builtin_memcpy(&u, &h, 2); return u;
}
static __device__ __forceinline__ float bff(u16 u) {
    __bf16 h; __builtin_memcpy(&h, &u, 2); return (float)h;
}
static __device__ __forceinline__ f32x4 MFMA(bf16x8 a, bf16x8 b, f32x4 c) {
    return __builtin_amdgcn_mfma_f32_16x16x32_bf16(a, b, c, 0, 0, 0);
}

// ---------------------------------------------------------------------------
__global__ __launch_bounds__(256) void zero_ws_kernel(float* __restrict__ p, int n) {
    int i = blockIdx.x * 256 + threadIdx.x;
    if (i < n) p[i] = 0.0f;
}

// ---------------------------------------------------------------------------
// Weight transform (r7-verified, unchanged).
__global__ __launch_bounds__(256) void wt_transform_kernel(
        const float* __restrict__ w, u16* __restrict__ wt) {
    int id = blockIdx.x * 256 + threadIdx.x;      // 110592
    int lane = id & 63;
    int rest = id >> 6;
    int tap = rest % 9;
    int rest2 = rest / 9;
    int ck = rest2 % 6, nt = rest2 / 6;
    int gate = nt & 3, cg = nt >> 2;
    int coutsub = lane & 15, kgl = lane >> 4;
    int oc = gate * COUT + cg * 16 + coutsub;
    int kh = tap / 3, kw = tap - kh * 3;
    size_t dst = ((size_t)(nt * 6 + ck) * 9 + tap) * 512 + lane * 8;
#pragma unroll
    for (int j = 0; j < 8; ++j) {
        int ch = ck * 32 + kgl * 8 + j;
        float wv = w[((oc * 192 + ch) * 3 + kh) * 3 + kw];
        float hh = (float)(__bf16)wv;
        float r1 = wv - hh;
        float ll = (float)(__bf16)r1;
        float r2 = r1 - ll;
        wt[dst + j]            = bfbits(hh);
        wt[WTPL + dst + j]     = bfbits(ll);
        wt[2 * WTPL + dst + j] = bfbits(r2);
    }
}

// ---------------------------------------------------------------------------
// Alpha neuron; spk1 [B][4][HW][16] (16-channel-blocked).
__global__ __launch_bounds__(256) void alpha_step_kernel(
        const float4* __restrict__ x_t,
        const float* __restrict__ p_alpha, const float* __restrict__ p_beta,
        const float* __restrict__ p_th1,
        float4* __restrict__ syn_e, float4* __restrict__ syn_i,
        u16* __restrict__ spk1h) {
#pragma clang fp contract(off)
    int q = blockIdx.x * 256 + threadIdx.x;       // 294912 quads
    float a = fminf(fmaxf(p_alpha[0], 1e-6f), 1.0f - 1e-6f);
    float b = fminf(fmaxf(p_beta[0],  1e-6f), 1.0f - 1e-6f);
    float la = logf(a), lb = logf(b);
    float tau = la / (lb - la);
    float th1 = p_th1[0];

    int bc = q / 576;                              // b*64 + c
    int hw0 = (q - bc * 576) * 4;
    int bb = bc >> 6, c = bc & 63;
    u16* sp = spk1h + ((size_t)(bb * 4 + (c >> 4)) * HW + hw0) * 16 + (c & 15);

    float4 xv = x_t[q], e4 = syn_e[q], i4 = syn_i[q];
    float pr0 = bff(sp[0]), pr1 = bff(sp[16]), pr2 = bff(sp[32]), pr3 = bff(sp[48]);
    float e, ii, m1;
    u16 s0, s1, s2, s3;
    e = a * e4.x + xv.x; ii = b * i4.x - xv.x; m1 = tau * (e + ii) - pr0 * th1;
    e4.x = e; i4.x = ii; s0 = (m1 - th1) > 0.0f ? 0x3F80u : 0u;
    e = a * e4.y + xv.y; ii = b * i4.y - xv.y; m1 = tau * (e + ii) - pr1 * th1;
    e4.y = e; i4.y = ii; s1 = (m1 - th1) > 0.0f ? 0x3F80u : 0u;
    e = a * e4.z + xv.z; ii = b * i4.z - xv.z; m1 = tau * (e + ii) - pr2 * th1;
    e4.z = e; i4.z = ii; s2 = (m1 - th1) > 0.0f ? 0x3F80u : 0u;
    e = a * e4.w + xv.w; ii = b * i4.w - xv.w; m1 = tau * (e + ii) - pr3 * th1;
    e4.w = e; i4.w = ii; s3 = (m1 - th1) > 0.0f ? 0x3F80u : 0u;
    syn_e[q] = e4; syn_i[q] = i4;
    sp[0] = s0; sp[16] = s1; sp[32] = s2; sp[48] = s3;
}

// ---------------------------------------------------------------------------
__global__ void t0_u_kernel(const float* __restrict__ b_conv, float* __restrict__ u) {
#pragma clang fp contract(off)
    int c = threadIdx.x;                           // 128
    float gi = b_conv[c], gf = b_conv[COUT + c];
    float gg = b_conv[2 * COUT + c], go = b_conv[3 * COUT + c];
    float si = 1.0f / (1.0f + expf(-gi));
    float sf = 1.0f / (1.0f + expf(-gf));
    float so = 1.0f / (1.0f + expf(-go));
    float tg = tanhf(gg);
    float s2 = sf * 0.0f + si * tg;
    float m2 = so * tanhf(s2);
    u[c] = s2;
    u16* uh = (u16*)(u + 128);
    float hh = (float)(__bf16)m2;
    float r1 = m2 - hh;
    float ll = (float)(__bf16)r1;
    float r2 = r1 - ll;
    uh[c] = bfbits(hh); uh[128 + c] = bfbits(ll); uh[256 + c] = bfbits(r2);
}

__global__ __launch_bounds__(256) void t0_fillA_kernel(
        const float* __restrict__ u, const float* __restrict__ bnb,
        float4* __restrict__ out0) {
    int i = blockIdx.x * 256 + threadIdx.x;        // 589824 quads
    int c = ((i * 4) / HW) % COUT;
    float bb = bnb[c];
    out0[i] = make_float4(bb, bb, bb, bb);
}

// t=0 fill B: m2 planes buffer 0 (16-ch-blocked) + syn2 (fragment layout).
__global__ __launch_bounds__(256) void t0_fillB_kernel(
        const float* __restrict__ u,
        u16* __restrict__ m2, float4* __restrict__ syn2) {
    int i = blockIdx.x * 256 + threadIdx.x;        // 589824
    const u16* uh = (const u16*)(u + 128);
    int pxg = i >> 2;
    int cg = (pxg / HW) & 7;
    int c0 = cg * 16 + (i & 3) * 4;
    *(uint2*)(m2 + (size_t)i * 4)             = *(const uint2*)(uh + c0);
    *(uint2*)(m2 + M2PL + (size_t)i * 4)      = *(const uint2*)(uh + 128 + c0);
    *(uint2*)(m2 + 2 * M2PL + (size_t)i * 4)  = *(const uint2*)(uh + 256 + c0);
    int csy = ((i >> 9) & 7) * 16 + (i & 15);
    float s2 = u[csy];
    syn2[i] = make_float4(s2, s2, s2, s2);
}

// ---------------------------------------------------------------------------
// MFMA conv + fused LSTM. Block: 4 waves, wave = 1 nt, M=128 px (8x16 tile).
// Grid 1152: bx = ntq*144 + mt*8 + b -> XCD = b.
#define LDSROW(P, r, kw) (*(const bf16x8*)&alds[P][(((r) * 18) + m16 + (kw)) * 32 + kg * 8])
__global__ __launch_bounds__(256, 3) void conv_lstm_fused(
        const u16* __restrict__ spk1h,
        const u16* __restrict__ m2rd,      // base of 3 contiguous planes
        const u16* __restrict__ wt,
        const float* __restrict__ bias, const float* __restrict__ p_th2,
        float* __restrict__ syn2,
        u16* __restrict__ m2wr,            // base of 3 contiguous planes
        u16* __restrict__ spk2h, int* __restrict__ cnt) {
    __shared__ __align__(16) u16 alds[3][APL];     // 34.6 KB; reused as f32 glds

    const int bx  = blockIdx.x;
    const int ntq = bx / 144;
    const int rm  = bx - ntq * 144;
    const int mt  = rm >> 3;
    const int b   = rm & 7;
    const int mt3 = mt / 3;
    const int h0 = mt3 * 8, w0 = (mt - mt3 * 3) * 16;

    const int tid = threadIdx.x;
    const int wn  = tid >> 6;
    const int lane = tid & 63;
    const int m16 = lane & 15;
    const int kg  = lane >> 4;
    const int nt = ntq * 4 + wn;

    f32x4 acc[8];
#pragma unroll
    for (int mf = 0; mf < 8; ++mf) acc[mf] = (f32x4){0.f, 0.f, 0.f, 0.f};

    // ---- hoisted mem2 staging indices ----
    int ldsM[9], srcM[9];
#pragma unroll
    for (int j = 0; j < 9; ++j) {
        int i = tid + j * 256;
        int pl = i / 720;
        int r = i - pl * 720;
        int px = r >> 2, qt = r & 3;
        int rr = px / 18, cc2 = px - rr * 18;
        int gh = h0 - 1 + rr, gw = w0 - 1 + cc2;
        ldsM[j] = (i < 2160) ? (pl * APL + px * 32 + qt * 8) : -1;
        bool ok = (i < 2160) && ((unsigned)gh < 48u) && ((unsigned)gw < 48u);
        srcM[j] = ok ? (pl * M2PL + ((b * 8 + (qt >> 1)) * HW + gh * 48 + gw) * 16
                        + (qt & 1) * 8) : -1;
    }

    // ---- binary staging: ck 0,1 -> planes 0,1 (one shot) ----
    {
        uint4 stB[6]; int ldsB[6];
#pragma unroll
        for (int j = 0; j < 6; ++j) {
            int i = tid + j * 256;
            int ckb = i / 720;
            int r = i - ckb * 720;
            int px = r >> 2, qt = r & 3;
            int rr = px / 18, cc2 = px - rr * 18;
            int gh = h0 - 1 + rr, gw = w0 - 1 + cc2;
            ldsB[j] = (i < 1440) ? (ckb * APL + px * 32 + qt * 8) : -1;
            uint4 v = make_uint4(0u, 0u, 0u, 0u);
            if (i < 1440 && (unsigned)gh < 48u && (unsigned)gw < 48u)
                v = *(const uint4*)(spk1h
                    + ((size_t)(b * 4 + ckb * 2 + (qt >> 1)) * HW + gh * 48 + gw) * 16
                    + (qt & 1) * 8);
            stB[j] = v;
        }
#pragma unroll
        for (int j = 0; j < 6; ++j)
            if (ldsB[j] >= 0) *(uint4*)&alds[0][ldsB[j]] = stB[j];
    }
    __syncthreads();

    uint4 stM[9];
#define LOADM(ck_)                                                           \
    {                                                                        \
        const int add = ((ck_) - 2) * (2 * HW * 16);                         \
        _Pragma("unroll")                                                    \
        for (int j = 0; j < 9; ++j) {                                        \
            uint4 v = make_uint4(0u, 0u, 0u, 0u);                            \
            if (srcM[j] >= 0) v = *(const uint4*)(m2rd + srcM[j] + add);     \
            stM[j] = v;                                                      \
        }                                                                    \
    }
#define WRITEM                                                               \
    {                                                                        \
        _Pragma("unroll")                                                    \
        for (int j = 0; j < 9; ++j)                                          \
            if (ldsM[j] >= 0) *(uint4*)&alds[0][ldsM[j]] = stM[j];           \
    }

    LOADM(2);                                      // in flight under binary compute

    // ---- binary compute (3-term), planes 0,1 ----
    for (int ckb = 0; ckb < 2; ++ckb) {
#pragma unroll
        for (int kw = 0; kw < 3; ++kw) {
            bf16x8 B0[3], B1[3], B2[3];
#pragma unroll
            for (int kh = 0; kh < 3; ++kh) {
                const size_t bo = ((size_t)(nt * 6 + ckb) * 9 + kh * 3 + kw) * 512 + lane * 8;
                B0[kh] = *(const bf16x8*)(wt + bo);
                B1[kh] = *(const bf16x8*)(wt + WTPL + bo);
                B2[kh] = *(const bf16x8*)(wt + 2 * WTPL + bo);
            }
            bf16x8 aw[3];
            aw[0] = LDSROW(ckb, 0, kw);
            aw[1] = LDSROW(ckb, 1, kw);
#pragma unroll
            for (int mf = 0; mf < 8; ++mf) {
                aw[(mf + 2) % 3] = LDSROW(ckb, mf + 2, kw);
#pragma unroll
                for (int kh = 0; kh < 3; ++kh) {
                    const bf16x8 A = aw[(mf + kh) % 3];
                    acc[mf] = MFMA(A, B0[kh], acc[mf]);
                    acc[mf] = MFMA(A, B1[kh], acc[mf]);
                    acc[mf] = MFMA(A, B2[kh], acc[mf]);
                }
            }
        }
    }

    // ---- mem2 chunks (7-term), pipelined staging ----
    for (int ck = 2; ck < 6; ++ck) {
        __syncthreads();
        WRITEM;
        __syncthreads();
        if (ck < 5) LOADM(ck + 1);
#pragma unroll
        for (int kw = 0; kw < 3; ++kw) {
            bf16x8 B0[3], B1[3], B2[3];
#pragma unroll
            for (int kh = 0; kh < 3; ++kh) {
                const size_t bo = ((size_t)(nt * 6 + ck) * 9 + kh * 3 + kw) * 512 + lane * 8;
                B0[kh] = *(const bf16x8*)(wt + bo);
                B1[kh] = *(const bf16x8*)(wt + WTPL + bo);
                B2[kh] = *(const bf16x8*)(wt + 2 * WTPL + bo);
            }
            bf16x8 a0[3], a1[3], a2[3];
            a0[0] = LDSROW(0, 0, kw); a0[1] = LDSROW(0, 1, kw);
            a1[0] = LDSROW(1, 0, kw); a1[1] = LDSROW(1, 1, kw);
            a2[0] = LDSROW(2, 0, kw); a2[1] = LDSROW(2, 1, kw);
#pragma unroll
            for (int mf = 0; mf < 8; ++mf) {
                const int sn = (mf + 2) % 3;
                a0[sn] = LDSROW(0, mf + 2, kw);
                a1[sn] = LDSROW(1, mf + 2, kw);
                a2[sn] = LDSROW(2, mf + 2, kw);
#pragma unroll
                for (int kh = 0; kh < 3; ++kh) {
                    const int s = (mf + kh) % 3;
                    acc[mf] = MFMA(a0[s], B0[kh], acc[mf]);
                    acc[mf] = MFMA(a0[s], B1[kh], acc[mf]);
                    acc[mf] = MFMA(a0[s], B2[kh], acc[mf]);
                    acc[mf] = MFMA(a1[s], B0[kh], acc[mf]);
                    acc[mf] = MFMA(a1[s], B1[kh], acc[mf]);
                    acc[mf] = MFMA(a2[s], B0[kh], acc[mf]);
                    acc[mf] = MFMA(a2[s], B1[kh], acc[mf]);
                }
            }
        }
    }

    // ---- gate exchange through LDS, then fused LSTM ----
    __syncthreads();
    {
        float* glds = (float*)alds;
#pragma unroll
        for (int mf = 0; mf < 8; ++mf)
            *(f32x4*)(glds + (wn * 8 + mf) * 256 + lane * 4) = acc[mf];
    }
    __syncthreads();
    {
#pragma clang fp contract(off)
        const float* glds = (const float*)alds;
        const int c = ntq * 16 + m16;
        const float th2 = p_th2[0];
        const float b0 = bias[c],       b1 = bias[128 + c];
        const float b2 = bias[256 + c], b3 = bias[384 + c];
        int sc = 0;
#pragma unroll
        for (int q = 0; q < 2; ++q) {
            const int mfq = wn * 2 + q;
            const f32x4 vI = *(const f32x4*)(glds + (0 * 8 + mfq) * 256 + lane * 4);
            const f32x4 vF = *(const f32x4*)(glds + (1 * 8 + mfq) * 256 + lane * 4);
            const f32x4 vG = *(const f32x4*)(glds + (2 * 8 + mfq) * 256 + lane * 4);
            const f32x4 vO = *(const f32x4*)(glds + (3 * 8 + mfq) * 256 + lane * 4);
            const size_t sidx = ((size_t)(((b * 18 + mt) * 8 + ntq) * 8 + mfq) * 64 + lane) * 4;
            const f32x4 s2v = *(const f32x4*)(syn2 + sidx);
            const int h = h0 + mfq;
            const size_t pixb = ((size_t)(b * 8 + ntq) * HW + h * 48 + w0 + kg * 4) * 16 + m16;
            f32x4 s2o;
#pragma unroll
            for (int j = 0; j < 4; ++j) {
                float gi = vI[j] + b0, gf = vF[j] + b1;
                float gg = vG[j] + b2, go = vO[j] + b3;
                float si = 1.0f / (1.0f + expf(-gi));
                float sf = 1.0f / (1.0f + expf(-gf));
                float so = 1.0f / (1.0f + expf(-go));
                float tg = tanhf(gg);
                float s2 = sf * s2v[j] + si * tg;
                float m2 = so * tanhf(s2);
                s2o[j] = s2;
                float hh = (float)(__bf16)m2;
                float r1 = m2 - hh;
                float ll = (float)(__bf16)r1;
                float r2 = r1 - ll;
                const size_t pix = pixb + (size_t)j * 16;
                m2wr[pix]             = bfbits(hh);
                m2wr[M2PL + pix]      = bfbits(ll);
                m2wr[2 * M2PL + pix]  = bfbits(r2);
                bool sp = (m2 - th2) > 0.0f;
                spk2h[pix] = sp ? 0x3F80u : 0u;
                sc += sp ? 1 : 0;
            }
            *(f32x4*)(syn2 + sidx) = s2o;
        }
        sc += __shfl_xor(sc, 16);
        sc += __shfl_xor(sc, 32);
        if (lane < 16) atomicAdd(&cnt[ntq * 16 + lane], sc);
    }
#undef LOADM
#undef WRITEM
}

// ---------------------------------------------------------------------------
// BN of binary spikes; spk2h is [B][8][HW][16].
__global__ __launch_bounds__(256) void bn_step_kernel(
        const u16* __restrict__ spk2h, const int* __restrict__ cnt,
        const float* __restrict__ gamma, const float* __restrict__ bnb,
        float4* __restrict__ out) {
#pragma clang fp contract(off)
    int i = blockIdx.x * 256 + threadIdx.x;        // 589824 quads (ch-major out)
    int e = i * 4;
    int tmp = e / HW;                               // b*128 + c
    int bb = tmp >> 7, c = tmp & 127;
    int hw0 = e - tmp * HW;
    const u16* sp = spk2h + ((size_t)(bb * 8 + (c >> 4)) * HW + hw0) * 16 + (c & 15);
    float mu  = (float)cnt[c] / (float)NPIX;
    float var = mu - mu * mu;
    float rs  = rsqrtf(var + 1e-5f);
    float g = gamma[c], bv = bnb[c];
    float s0 = bff(sp[0]), s1 = bff(sp[16]), s2 = bff(sp[32]), s3 = bff(sp[48]);
    out[i] = make_float4(g * (s0 - mu) * rs + bv, g * (s1 - mu) * rs + bv,
                         g * (s2 - mu) * rs + bv, g * (s3 - mu) * rs + bv);
}

// ---------------------------------------------------------------------------
extern "C" void kernel_launch(void* const* d_in, const int* in_sizes, int n_in,
                              void* d_out, int out_size, void* d_ws, size_t ws_size,
                              hipStream_t stream) {
    const float* x       = (const float*)d_in[0];
    const float* p_alpha = (const float*)d_in[1];
    const float* p_beta  = (const float*)d_in[2];
    const float* p_th1   = (const float*)d_in[3];
    const float* p_th2   = (const float*)d_in[4];
    const float* w_conv  = (const float*)d_in[5];
    const float* b_conv  = (const float*)d_in[6];
    const float* gamma   = (const float*)d_in[7];
    const float* bn_beta = (const float*)d_in[8];
    float* out = (float*)d_out;

    float* wsf   = (float*)d_ws;
    float* syn_e = wsf + OFF_SYNE;
    float* syn_i = wsf + OFF_SYNI;
    u16*   spk1h = (u16*)(wsf + OFF_SPK1H);
    int*   cnt   = (int*)(wsf + OFF_CNT);
    float* syn2  = wsf + OFF_SYN2;
    u16*   spk2h = (u16*)(wsf + OFF_SPK2H);
    u16*   m2buf[2] = {(u16*)(wsf + OFF_M2H0), (u16*)(wsf + OFF_M2H1)};
    u16*   wt    = (u16*)(wsf + OFF_WT);
    float* u     = wsf + OFF_U;

    zero_ws_kernel<<<ZERO_W / 256, 256, 0, stream>>>(wsf, ZERO_W);
    wt_transform_kernel<<<432, 256, 0, stream>>>(w_conv, wt);

    // ---- t = 0 (algebraic) ----
    alpha_step_kernel<<<1152, 256, 0, stream>>>(
        (const float4*)x, p_alpha, p_beta, p_th1,
        (float4*)syn_e, (float4*)syn_i, spk1h);
    t0_u_kernel<<<1, COUT, 0, stream>>>(b_conv, u);
    t0_fillA_kernel<<<2304, 256, 0, stream>>>(u, bn_beta, (float4*)out);
    t0_fillB_kernel<<<2304, 256, 0, stream>>>(u, m2buf[0], (float4*)syn2);

    // ---- t = 1..3 ----
    for (int t = 1; t < T_; ++t) {
        const int rd = (t - 1) & 1, wr = t & 1;
        alpha_step_kernel<<<1152, 256, 0, stream>>>(
            (const float4*)(x + (size_t)t * 1179648), p_alpha, p_beta, p_th1,
            (float4*)syn_e, (float4*)syn_i, spk1h);
        conv_lstm_fused<<<1152, 256, 0, stream>>>(
            spk1h, m2buf[rd], wt, b_conv, p_th2,
            syn2, m2buf[wr], spk2h, cnt + t * COUT);
        bn_step_kernel<<<2304, 256, 0, stream>>>(
            spk2h, cnt + t * COUT, gamma, bn_beta,
            (float4*)(out + (size_t)t * 2359296));
    }
}

// Round 15
// 482.841 us; speedup vs baseline: 1.2928x; 1.1496x over previous
//
#include <hip/hip_runtime.h>

// ---------------------------------------------------------------------------
// snnBlock, round 15: exact revert to the round-11 optimum (482 µs measured).
// r12 (rotation, setprio), r13 (LDS diet + (256,4) reg-squeeze) and r14
// (LDS diet + (256,3)) all regressed for one consistent reason: per-XCD L2
// capacity (~4MB) is saturated at 3 blocks/CU with coherent phases; any
// added concurrency or phase skew thrashes L2 and costs more than the
// barrier stall it hides. This is the measured best configuration.
// ---------------------------------------------------------------------------

typedef unsigned short u16;
typedef __attribute__((ext_vector_type(8))) __bf16 bf16x8;
typedef __attribute__((ext_vector_type(4))) float   f32x4;

#define T_ 4
#define B_ 8
#define CIN 64
#define COUT 128
#define H_ 48
#define W_ 48
#define HW 2304
#define NPIX 18432
#define KTOT 1728
#define WTPL 884736            // elements per weight plane
#define M2PL 2359296           // u16 per m2 plane [B][8][HW][16]

// ---- workspace layout (32-bit words) ----
#define OFF_SYNE  0
#define OFF_SYNI  1179648
#define OFF_SPK1H 2359296      // bf16 [B][4][HW][16]
#define OFF_CNT   2949120      // int [T][128]
#define ZERO_W    2949632
#define OFF_SYN2  2949632      // f32 fragment layout (2359296 words)
#define OFF_SPK2H 5308928      // bf16 [B][8][HW][16]
#define OFF_M2H0  6488576      // 3 contiguous planes, buffer 0
#define OFF_M2H1  10027520     // 3 contiguous planes, buffer 1
#define OFF_WT    13566464     // bf16 [3][884736]
#define OFF_U     14893568

static __device__ __forceinline__ u16 bfbits(float f) {
    __bf16 h = (__bf16)f; u16 u; __builtin_memcpy(&u, &h, 2); return u;
}
static __device__ __forceinline__ float bff(u16 u) {
    __bf16 h; __builtin_memcpy(&h, &u, 2); return (float)h;
}
static __device__ __forceinline__ f32x4 MFMA(bf16x8 a, bf16x8 b, f32x4 c) {
    return __builtin_amdgcn_mfma_f32_16x16x32_bf16(a, b, c, 0, 0, 0);
}

// ---------------------------------------------------------------------------
__global__ __launch_bounds__(256) void zero_ws_kernel(float* __restrict__ p, int n) {
    int i = blockIdx.x * 256 + threadIdx.x;
    if (i < n) p[i] = 0.0f;
}

// ---------------------------------------------------------------------------
// Weight transform (r7-verified, unchanged).
__global__ __launch_bounds__(256) void wt_transform_kernel(
        const float* __restrict__ w, u16* __restrict__ wt) {
    int id = blockIdx.x * 256 + threadIdx.x;      // 110592
    int lane = id & 63;
    int rest = id >> 6;
    int tap = rest % 9;
    int rest2 = rest / 9;
    int ck = rest2 % 6, nt = rest2 / 6;
    int gate = nt & 3, cg = nt >> 2;
    int coutsub = lane & 15, kgl = lane >> 4;
    int oc = gate * COUT + cg * 16 + coutsub;
    int kh = tap / 3, kw = tap - kh * 3;
    size_t dst = ((size_t)(nt * 6 + ck) * 9 + tap) * 512 + lane * 8;
#pragma unroll
    for (int j = 0; j < 8; ++j) {
        int ch = ck * 32 + kgl * 8 + j;
        float wv = w[((oc * 192 + ch) * 3 + kh) * 3 + kw];
        float hh = (float)(__bf16)wv;
        float r1 = wv - hh;
        float ll = (float)(__bf16)r1;
        float r2 = r1 - ll;
        wt[dst + j]            = bfbits(hh);
        wt[WTPL + dst + j]     = bfbits(ll);
        wt[2 * WTPL + dst + j] = bfbits(r2);
    }
}

// ---------------------------------------------------------------------------
// Alpha neuron; spk1 [B][4][HW][16] (16-channel-blocked).
__global__ __launch_bounds__(256) void alpha_step_kernel(
        const float4* __restrict__ x_t,
        const float* __restrict__ p_alpha, const float* __restrict__ p_beta,
        const float* __restrict__ p_th1,
        float4* __restrict__ syn_e, float4* __restrict__ syn_i,
        u16* __restrict__ spk1h) {
#pragma clang fp contract(off)
    int q = blockIdx.x * 256 + threadIdx.x;       // 294912 quads
    float a = fminf(fmaxf(p_alpha[0], 1e-6f), 1.0f - 1e-6f);
    float b = fminf(fmaxf(p_beta[0],  1e-6f), 1.0f - 1e-6f);
    float la = logf(a), lb = logf(b);
    float tau = la / (lb - la);
    float th1 = p_th1[0];

    int bc = q / 576;                              // b*64 + c
    int hw0 = (q - bc * 576) * 4;
    int bb = bc >> 6, c = bc & 63;
    u16* sp = spk1h + ((size_t)(bb * 4 + (c >> 4)) * HW + hw0) * 16 + (c & 15);

    float4 xv = x_t[q], e4 = syn_e[q], i4 = syn_i[q];
    float pr0 = bff(sp[0]), pr1 = bff(sp[16]), pr2 = bff(sp[32]), pr3 = bff(sp[48]);
    float e, ii, m1;
    u16 s0, s1, s2, s3;
    e = a * e4.x + xv.x; ii = b * i4.x - xv.x; m1 = tau * (e + ii) - pr0 * th1;
    e4.x = e; i4.x = ii; s0 = (m1 - th1) > 0.0f ? 0x3F80u : 0u;
    e = a * e4.y + xv.y; ii = b * i4.y - xv.y; m1 = tau * (e + ii) - pr1 * th1;
    e4.y = e; i4.y = ii; s1 = (m1 - th1) > 0.0f ? 0x3F80u : 0u;
    e = a * e4.z + xv.z; ii = b * i4.z - xv.z; m1 = tau * (e + ii) - pr2 * th1;
    e4.z = e; i4.z = ii; s2 = (m1 - th1) > 0.0f ? 0x3F80u : 0u;
    e = a * e4.w + xv.w; ii = b * i4.w - xv.w; m1 = tau * (e + ii) - pr3 * th1;
    e4.w = e; i4.w = ii; s3 = (m1 - th1) > 0.0f ? 0x3F80u : 0u;
    syn_e[q] = e4; syn_i[q] = i4;
    sp[0] = s0; sp[16] = s1; sp[32] = s2; sp[48] = s3;
}

// ---------------------------------------------------------------------------
__global__ void t0_u_kernel(const float* __restrict__ b_conv, float* __restrict__ u) {
#pragma clang fp contract(off)
    int c = threadIdx.x;                           // 128
    float gi = b_conv[c], gf = b_conv[COUT + c];
    float gg = b_conv[2 * COUT + c], go = b_conv[3 * COUT + c];
    float si = 1.0f / (1.0f + expf(-gi));
    float sf = 1.0f / (1.0f + expf(-gf));
    float so = 1.0f / (1.0f + expf(-go));
    float tg = tanhf(gg);
    float s2 = sf * 0.0f + si * tg;
    float m2 = so * tanhf(s2);
    u[c] = s2;
    u16* uh = (u16*)(u + 128);
    float hh = (float)(__bf16)m2;
    float r1 = m2 - hh;
    float ll = (float)(__bf16)r1;
    float r2 = r1 - ll;
    uh[c] = bfbits(hh); uh[128 + c] = bfbits(ll); uh[256 + c] = bfbits(r2);
}

__global__ __launch_bounds__(256) void t0_fillA_kernel(
        const float* __restrict__ u, const float* __restrict__ bnb,
        float4* __restrict__ out0) {
    int i = blockIdx.x * 256 + threadIdx.x;        // 589824 quads
    int c = ((i * 4) / HW) % COUT;
    float bb = bnb[c];
    out0[i] = make_float4(bb, bb, bb, bb);
}

// t=0 fill B: m2 planes buffer 0 (16-ch-blocked) + syn2 (fragment layout).
__global__ __launch_bounds__(256) void t0_fillB_kernel(
        const float* __restrict__ u,
        u16* __restrict__ m2, float4* __restrict__ syn2) {
    int i = blockIdx.x * 256 + threadIdx.x;        // 589824
    const u16* uh = (const u16*)(u + 128);
    int pxg = i >> 2;
    int cg = (pxg / HW) & 7;
    int c0 = cg * 16 + (i & 3) * 4;
    *(uint2*)(m2 + (size_t)i * 4)             = *(const uint2*)(uh + c0);
    *(uint2*)(m2 + M2PL + (size_t)i * 4)      = *(const uint2*)(uh + 128 + c0);
    *(uint2*)(m2 + 2 * M2PL + (size_t)i * 4)  = *(const uint2*)(uh + 256 + c0);
    int csy = ((i >> 9) & 7) * 16 + (i & 15);
    float s2 = u[csy];
    syn2[i] = make_float4(s2, s2, s2, s2);
}

// ---------------------------------------------------------------------------
// MFMA conv + fused LSTM. Block: 4 waves, wave = 1 nt, M=128 px (8x16 tile).
// Grid 1152: bx = ntq*144 + mt*8 + b -> XCD = b.
#define LDSROW(P, r, kw) (*(const bf16x8*)&alds[P][(((r) * 18) + m16 + (kw)) * 40 + kg * 8])
__global__ __launch_bounds__(256, 3) void conv_lstm_fused(
        const u16* __restrict__ spk1h,
        const u16* __restrict__ m2rd,      // base of 3 contiguous planes
        const u16* __restrict__ wt,
        const float* __restrict__ bias, const float* __restrict__ p_th2,
        float* __restrict__ syn2,
        u16* __restrict__ m2wr,            // base of 3 contiguous planes
        u16* __restrict__ spk2h, int* __restrict__ cnt) {
    __shared__ __align__(16) u16 alds[3][7200];    // 43.2 KB; reused as f32 glds

    const int bx  = blockIdx.x;
    const int ntq = bx / 144;
    const int rm  = bx - ntq * 144;
    const int mt  = rm >> 3;
    const int b   = rm & 7;
    const int mt3 = mt / 3;
    const int h0 = mt3 * 8, w0 = (mt - mt3 * 3) * 16;

    const int tid = threadIdx.x;
    const int wn  = tid >> 6;
    const int lane = tid & 63;
    const int m16 = lane & 15;
    const int kg  = lane >> 4;
    const int nt = ntq * 4 + wn;

    f32x4 acc[8];
#pragma unroll
    for (int mf = 0; mf < 8; ++mf) acc[mf] = (f32x4){0.f, 0.f, 0.f, 0.f};

    // ---- hoisted mem2 staging indices ----
    int ldsM[9], srcM[9];
#pragma unroll
    for (int j = 0; j < 9; ++j) {
        int i = tid + j * 256;
        int pl = i / 720;
        int r = i - pl * 720;
        int px = r >> 2, qt = r & 3;
        int rr = px / 18, cc2 = px - rr * 18;
        int gh = h0 - 1 + rr, gw = w0 - 1 + cc2;
        ldsM[j] = (i < 2160) ? (pl * 7200 + px * 40 + qt * 8) : -1;
        bool ok = (i < 2160) && ((unsigned)gh < 48u) && ((unsigned)gw < 48u);
        srcM[j] = ok ? (pl * M2PL + ((b * 8 + (qt >> 1)) * HW + gh * 48 + gw) * 16
                        + (qt & 1) * 8) : -1;
    }

    // ---- binary staging: ck 0,1 -> planes 0,1 (one shot) ----
    {
        uint4 stB[6]; int ldsB[6];
#pragma unroll
        for (int j = 0; j < 6; ++j) {
            int i = tid + j * 256;
            int ckb = i / 720;
            int r = i - ckb * 720;
            int px = r >> 2, qt = r & 3;
            int rr = px / 18, cc2 = px - rr * 18;
            int gh = h0 - 1 + rr, gw = w0 - 1 + cc2;
            ldsB[j] = (i < 1440) ? (ckb * 7200 + px * 40 + qt * 8) : -1;
            uint4 v = make_uint4(0u, 0u, 0u, 0u);
            if (i < 1440 && (unsigned)gh < 48u && (unsigned)gw < 48u)
                v = *(const uint4*)(spk1h
                    + ((size_t)(b * 4 + ckb * 2 + (qt >> 1)) * HW + gh * 48 + gw) * 16
                    + (qt & 1) * 8);
            stB[j] = v;
        }
#pragma unroll
        for (int j = 0; j < 6; ++j)
            if (ldsB[j] >= 0) *(uint4*)&alds[0][ldsB[j]] = stB[j];
    }
    __syncthreads();

    uint4 stM[9];
#define LOADM(ck_)                                                           \
    {                                                                        \
        const int add = ((ck_) - 2) * (2 * HW * 16);                         \
        _Pragma("unroll")                                                    \
        for (int j = 0; j < 9; ++j) {                                        \
            uint4 v = make_uint4(0u, 0u, 0u, 0u);                            \
            if (srcM[j] >= 0) v = *(const uint4*)(m2rd + srcM[j] + add);     \
            stM[j] = v;                                                      \
        }                                                                    \
    }
#define WRITEM                                                               \
    {                                                                        \
        _Pragma("unroll")                                                    \
        for (int j = 0; j < 9; ++j)                                          \
            if (ldsM[j] >= 0) *(uint4*)&alds[0][ldsM[j]] = stM[j];           \
    }

    LOADM(2);                                      // in flight under binary compute

    // ---- binary compute (3-term), planes 0,1 ----
    for (int ckb = 0; ckb < 2; ++ckb) {
#pragma unroll
        for (int kw = 0; kw < 3; ++kw) {
            bf16x8 B0[3], B1[3], B2[3];
#pragma unroll
            for (int kh = 0; kh < 3; ++kh) {
                const size_t bo = ((size_t)(nt * 6 + ckb) * 9 + kh * 3 + kw) * 512 + lane * 8;
                B0[kh] = *(const bf16x8*)(wt + bo);
                B1[kh] = *(const bf16x8*)(wt + WTPL + bo);
                B2[kh] = *(const bf16x8*)(wt + 2 * WTPL + bo);
            }
            bf16x8 aw[3];
            aw[0] = LDSROW(ckb, 0, kw);
            aw[1] = LDSROW(ckb, 1, kw);
#pragma unroll
            for (int mf = 0; mf < 8; ++mf) {
                aw[(mf + 2) % 3] = LDSROW(ckb, mf + 2, kw);
#pragma unroll
                for (int kh = 0; kh < 3; ++kh) {
                    const bf16x8 A = aw[(mf + kh) % 3];
                    acc[mf] = MFMA(A, B0[kh], acc[mf]);
                    acc[mf] = MFMA(A, B1[kh], acc[mf]);
                    acc[mf] = MFMA(A, B2[kh], acc[mf]);
                }
            }
        }
    }

    // ---- mem2 chunks (7-term), pipelined staging ----
    for (int ck = 2; ck < 6; ++ck) {
        __syncthreads();
        WRITEM;
        __syncthreads();
        if (ck < 5) LOADM(ck + 1);
#pragma unroll
        for (int kw = 0; kw < 3; ++kw) {
            bf16x8 B0[3], B1[3], B2[3];
#pragma unroll
            for (int kh = 0; kh < 3; ++kh) {
                const size_t bo = ((size_t)(nt * 6 + ck) * 9 + kh * 3 + kw) * 512 + lane * 8;
                B0[kh] = *(const bf16x8*)(wt + bo);
                B1[kh] = *(const bf16x8*)(wt + WTPL + bo);
                B2[kh] = *(const bf16x8*)(wt + 2 * WTPL + bo);
            }
            bf16x8 a0[3], a1[3], a2[3];
            a0[0] = LDSROW(0, 0, kw); a0[1] = LDSROW(0, 1, kw);
            a1[0] = LDSROW(1, 0, kw); a1[1] = LDSROW(1, 1, kw);
            a2[0] = LDSROW(2, 0, kw); a2[1] = LDSROW(2, 1, kw);
#pragma unroll
            for (int mf = 0; mf < 8; ++mf) {
                const int sn = (mf + 2) % 3;
                a0[sn] = LDSROW(0, mf + 2, kw);
                a1[sn] = LDSROW(1, mf + 2, kw);
                a2[sn] = LDSROW(2, mf + 2, kw);
#pragma unroll
                for (int kh = 0; kh < 3; ++kh) {
                    const int s = (mf + kh) % 3;
                    acc[mf] = MFMA(a0[s], B0[kh], acc[mf]);
                    acc[mf] = MFMA(a0[s], B1[kh], acc[mf]);
                    acc[mf] = MFMA(a0[s], B2[kh], acc[mf]);
                    acc[mf] = MFMA(a1[s], B0[kh], acc[mf]);
                    acc[mf] = MFMA(a1[s], B1[kh], acc[mf]);
                    acc[mf] = MFMA(a2[s], B0[kh], acc[mf]);
                    acc[mf] = MFMA(a2[s], B1[kh], acc[mf]);
                }
            }
        }
    }

    // ---- gate exchange through LDS, then fused LSTM ----
    __syncthreads();
    {
        float* glds = (float*)alds;
#pragma unroll
        for (int mf = 0; mf < 8; ++mf)
            *(f32x4*)(glds + (wn * 8 + mf) * 256 + lane * 4) = acc[mf];
    }
    __syncthreads();
    {
#pragma clang fp contract(off)
        const float* glds = (const float*)alds;
        const int c = ntq * 16 + m16;
        const float th2 = p_th2[0];
        const float b0 = bias[c],       b1 = bias[128 + c];
        const float b2 = bias[256 + c], b3 = bias[384 + c];
        int sc = 0;
#pragma unroll
        for (int q = 0; q < 2; ++q) {
            const int mfq = wn * 2 + q;
            const f32x4 vI = *(const f32x4*)(glds + (0 * 8 + mfq) * 256 + lane * 4);
            const f32x4 vF = *(const f32x4*)(glds + (1 * 8 + mfq) * 256 + lane * 4);
            const f32x4 vG = *(const f32x4*)(glds + (2 * 8 + mfq) * 256 + lane * 4);
            const f32x4 vO = *(const f32x4*)(glds + (3 * 8 + mfq) * 256 + lane * 4);
            const size_t sidx = ((size_t)(((b * 18 + mt) * 8 + ntq) * 8 + mfq) * 64 + lane) * 4;
            const f32x4 s2v = *(const f32x4*)(syn2 + sidx);
            const int h = h0 + mfq;
            const size_t pixb = ((size_t)(b * 8 + ntq) * HW + h * 48 + w0 + kg * 4) * 16 + m16;
            f32x4 s2o;
#pragma unroll
            for (int j = 0; j < 4; ++j) {
                float gi = vI[j] + b0, gf = vF[j] + b1;
                float gg = vG[j] + b2, go = vO[j] + b3;
                float si = 1.0f / (1.0f + expf(-gi));
                float sf = 1.0f / (1.0f + expf(-gf));
                float so = 1.0f / (1.0f + expf(-go));
                float tg = tanhf(gg);
                float s2 = sf * s2v[j] + si * tg;
                float m2 = so * tanhf(s2);
                s2o[j] = s2;
                float hh = (float)(__bf16)m2;
                float r1 = m2 - hh;
                float ll = (float)(__bf16)r1;
                float r2 = r1 - ll;
                const size_t pix = pixb + (size_t)j * 16;
                m2wr[pix]             = bfbits(hh);
                m2wr[M2PL + pix]      = bfbits(ll);
                m2wr[2 * M2PL + pix]  = bfbits(r2);
                bool sp = (m2 - th2) > 0.0f;
                spk2h[pix] = sp ? 0x3F80u : 0u;
                sc += sp ? 1 : 0;
            }
            *(f32x4*)(syn2 + sidx) = s2o;
        }
        sc += __shfl_xor(sc, 16);
        sc += __shfl_xor(sc, 32);
        if (lane < 16) atomicAdd(&cnt[ntq * 16 + lane], sc);
    }
#undef LOADM
#undef WRITEM
}

// ---------------------------------------------------------------------------
// BN of binary spikes; spk2h is [B][8][HW][16].
__global__ __launch_bounds__(256) void bn_step_kernel(
        const u16* __restrict__ spk2h, const int* __restrict__ cnt,
        const float* __restrict__ gamma, const float* __restrict__ bnb,
        float4* __restrict__ out) {
#pragma clang fp contract(off)
    int i = blockIdx.x * 256 + threadIdx.x;        // 589824 quads (ch-major out)
    int e = i * 4;
    int tmp = e / HW;                               // b*128 + c
    int bb = tmp >> 7, c = tmp & 127;
    int hw0 = e - tmp * HW;
    const u16* sp = spk2h + ((size_t)(bb * 8 + (c >> 4)) * HW + hw0) * 16 + (c & 15);
    float mu  = (float)cnt[c] / (float)NPIX;
    float var = mu - mu * mu;
    float rs  = rsqrtf(var + 1e-5f);
    float g = gamma[c], bv = bnb[c];
    float s0 = bff(sp[0]), s1 = bff(sp[16]), s2 = bff(sp[32]), s3 = bff(sp[48]);
    out[i] = make_float4(g * (s0 - mu) * rs + bv, g * (s1 - mu) * rs + bv,
                         g * (s2 - mu) * rs + bv, g * (s3 - mu) * rs + bv);
}

// ---------------------------------------------------------------------------
extern "C" void kernel_launch(void* const* d_in, const int* in_sizes, int n_in,
                              void* d_out, int out_size, void* d_ws, size_t ws_size,
                              hipStream_t stream) {
    const float* x       = (const float*)d_in[0];
    const float* p_alpha = (const float*)d_in[1];
    const float* p_beta  = (const float*)d_in[2];
    const float* p_th1   = (const float*)d_in[3];
    const float* p_th2   = (const float*)d_in[4];
    const float* w_conv  = (const float*)d_in[5];
    const float* b_conv  = (const float*)d_in[6];
    const float* gamma   = (const float*)d_in[7];
    const float* bn_beta = (const float*)d_in[8];
    float* out = (float*)d_out;

    float* wsf   = (float*)d_ws;
    float* syn_e = wsf + OFF_SYNE;
    float* syn_i = wsf + OFF_SYNI;
    u16*   spk1h = (u16*)(wsf + OFF_SPK1H);
    int*   cnt   = (int*)(wsf + OFF_CNT);
    float* syn2  = wsf + OFF_SYN2;
    u16*   spk2h = (u16*)(wsf + OFF_SPK2H);
    u16*   m2buf[2] = {(u16*)(wsf + OFF_M2H0), (u16*)(wsf + OFF_M2H1)};
    u16*   wt    = (u16*)(wsf + OFF_WT);
    float* u     = wsf + OFF_U;

    zero_ws_kernel<<<ZERO_W / 256, 256, 0, stream>>>(wsf, ZERO_W);
    wt_transform_kernel<<<432, 256, 0, stream>>>(w_conv, wt);

    // ---- t = 0 (algebraic) ----
    alpha_step_kernel<<<1152, 256, 0, stream>>>(
        (const float4*)x, p_alpha, p_beta, p_th1,
        (float4*)syn_e, (float4*)syn_i, spk1h);
    t0_u_kernel<<<1, COUT, 0, stream>>>(b_conv, u);
    t0_fillA_kernel<<<2304, 256, 0, stream>>>(u, bn_beta, (float4*)out);
    t0_fillB_kernel<<<2304, 256, 0, stream>>>(u, m2buf[0], (float4*)syn2);

    // ---- t = 1..3 ----
    for (int t = 1; t < T_; ++t) {
        const int rd = (t - 1) & 1, wr = t & 1;
        alpha_step_kernel<<<1152, 256, 0, stream>>>(
            (const float4*)(x + (size_t)t * 1179648), p_alpha, p_beta, p_th1,
            (float4*)syn_e, (float4*)syn_i, spk1h);
        conv_lstm_fused<<<1152, 256, 0, stream>>>(
            spk1h, m2buf[rd], wt, b_conv, p_th2,
            syn2, m2buf[wr], spk2h, cnt + t * COUT);
        bn_step_kernel<<<2304, 256, 0, stream>>>(
            spk2h, cnt + t * COUT, gamma, bn_beta,
            (float4*)(out + (size_t)t * 2359296));
    }
}

// Round 16
// 460.361 us; speedup vs baseline: 1.3559x; 1.0488x over previous
//
#include <hip/hip_runtime.h>

// ---------------------------------------------------------------------------
// snnBlock, round 16: r11/r15 optimum with the mem2 split trimmed 7 -> 6
// terms. The dropped term l2*wl is ~2^-27 relative — the SAME magnitude as
// l*wl2 which the 7-term path already drops; total error stays in the
// ~2^-27 class that has measured absmax 0.0 since round 7. MFMA/wave
// 2448 -> 2160 (-11.8%).
// Everything else byte-identical to the round-15 verified kernel.
// ---------------------------------------------------------------------------

typedef unsigned short u16;
typedef __attribute__((ext_vector_type(8))) __bf16 bf16x8;
typedef __attribute__((ext_vector_type(4))) float   f32x4;

#define T_ 4
#define B_ 8
#define CIN 64
#define COUT 128
#define H_ 48
#define W_ 48
#define HW 2304
#define NPIX 18432
#define KTOT 1728
#define WTPL 884736            // elements per weight plane
#define M2PL 2359296           // u16 per m2 plane [B][8][HW][16]

// ---- workspace layout (32-bit words) ----
#define OFF_SYNE  0
#define OFF_SYNI  1179648
#define OFF_SPK1H 2359296      // bf16 [B][4][HW][16]
#define OFF_CNT   2949120      // int [T][128]
#define ZERO_W    2949632
#define OFF_SYN2  2949632      // f32 fragment layout (2359296 words)
#define OFF_SPK2H 5308928      // bf16 [B][8][HW][16]
#define OFF_M2H0  6488576      // 3 contiguous planes, buffer 0
#define OFF_M2H1  10027520     // 3 contiguous planes, buffer 1
#define OFF_WT    13566464     // bf16 [3][884736]
#define OFF_U     14893568

static __device__ __forceinline__ u16 bfbits(float f) {
    __bf16 h = (__bf16)f; u16 u; __builtin_memcpy(&u, &h, 2); return u;
}
static __device__ __forceinline__ float bff(u16 u) {
    __bf16 h; __builtin_memcpy(&h, &u, 2); return (float)h;
}
static __device__ __forceinline__ f32x4 MFMA(bf16x8 a, bf16x8 b, f32x4 c) {
    return __builtin_amdgcn_mfma_f32_16x16x32_bf16(a, b, c, 0, 0, 0);
}

// ---------------------------------------------------------------------------
__global__ __launch_bounds__(256) void zero_ws_kernel(float* __restrict__ p, int n) {
    int i = blockIdx.x * 256 + threadIdx.x;
    if (i < n) p[i] = 0.0f;
}

// ---------------------------------------------------------------------------
// Weight transform (r7-verified, unchanged).
__global__ __launch_bounds__(256) void wt_transform_kernel(
        const float* __restrict__ w, u16* __restrict__ wt) {
    int id = blockIdx.x * 256 + threadIdx.x;      // 110592
    int lane = id & 63;
    int rest = id >> 6;
    int tap = rest % 9;
    int rest2 = rest / 9;
    int ck = rest2 % 6, nt = rest2 / 6;
    int gate = nt & 3, cg = nt >> 2;
    int coutsub = lane & 15, kgl = lane >> 4;
    int oc = gate * COUT + cg * 16 + coutsub;
    int kh = tap / 3, kw = tap - kh * 3;
    size_t dst = ((size_t)(nt * 6 + ck) * 9 + tap) * 512 + lane * 8;
#pragma unroll
    for (int j = 0; j < 8; ++j) {
        int ch = ck * 32 + kgl * 8 + j;
        float wv = w[((oc * 192 + ch) * 3 + kh) * 3 + kw];
        float hh = (float)(__bf16)wv;
        float r1 = wv - hh;
        float ll = (float)(__bf16)r1;
        float r2 = r1 - ll;
        wt[dst + j]            = bfbits(hh);
        wt[WTPL + dst + j]     = bfbits(ll);
        wt[2 * WTPL + dst + j] = bfbits(r2);
    }
}

// ---------------------------------------------------------------------------
// Alpha neuron; spk1 [B][4][HW][16] (16-channel-blocked).
__global__ __launch_bounds__(256) void alpha_step_kernel(
        const float4* __restrict__ x_t,
        const float* __restrict__ p_alpha, const float* __restrict__ p_beta,
        const float* __restrict__ p_th1,
        float4* __restrict__ syn_e, float4* __restrict__ syn_i,
        u16* __restrict__ spk1h) {
#pragma clang fp contract(off)
    int q = blockIdx.x * 256 + threadIdx.x;       // 294912 quads
    float a = fminf(fmaxf(p_alpha[0], 1e-6f), 1.0f - 1e-6f);
    float b = fminf(fmaxf(p_beta[0],  1e-6f), 1.0f - 1e-6f);
    float la = logf(a), lb = logf(b);
    float tau = la / (lb - la);
    float th1 = p_th1[0];

    int bc = q / 576;                              // b*64 + c
    int hw0 = (q - bc * 576) * 4;
    int bb = bc >> 6, c = bc & 63;
    u16* sp = spk1h + ((size_t)(bb * 4 + (c >> 4)) * HW + hw0) * 16 + (c & 15);

    float4 xv = x_t[q], e4 = syn_e[q], i4 = syn_i[q];
    float pr0 = bff(sp[0]), pr1 = bff(sp[16]), pr2 = bff(sp[32]), pr3 = bff(sp[48]);
    float e, ii, m1;
    u16 s0, s1, s2, s3;
    e = a * e4.x + xv.x; ii = b * i4.x - xv.x; m1 = tau * (e + ii) - pr0 * th1;
    e4.x = e; i4.x = ii; s0 = (m1 - th1) > 0.0f ? 0x3F80u : 0u;
    e = a * e4.y + xv.y; ii = b * i4.y - xv.y; m1 = tau * (e + ii) - pr1 * th1;
    e4.y = e; i4.y = ii; s1 = (m1 - th1) > 0.0f ? 0x3F80u : 0u;
    e = a * e4.z + xv.z; ii = b * i4.z - xv.z; m1 = tau * (e + ii) - pr2 * th1;
    e4.z = e; i4.z = ii; s2 = (m1 - th1) > 0.0f ? 0x3F80u : 0u;
    e = a * e4.w + xv.w; ii = b * i4.w - xv.w; m1 = tau * (e + ii) - pr3 * th1;
    e4.w = e; i4.w = ii; s3 = (m1 - th1) > 0.0f ? 0x3F80u : 0u;
    syn_e[q] = e4; syn_i[q] = i4;
    sp[0] = s0; sp[16] = s1; sp[32] = s2; sp[48] = s3;
}

// ---------------------------------------------------------------------------
__global__ void t0_u_kernel(const float* __restrict__ b_conv, float* __restrict__ u) {
#pragma clang fp contract(off)
    int c = threadIdx.x;                           // 128
    float gi = b_conv[c], gf = b_conv[COUT + c];
    float gg = b_conv[2 * COUT + c], go = b_conv[3 * COUT + c];
    float si = 1.0f / (1.0f + expf(-gi));
    float sf = 1.0f / (1.0f + expf(-gf));
    float so = 1.0f / (1.0f + expf(-go));
    float tg = tanhf(gg);
    float s2 = sf * 0.0f + si * tg;
    float m2 = so * tanhf(s2);
    u[c] = s2;
    u16* uh = (u16*)(u + 128);
    float hh = (float)(__bf16)m2;
    float r1 = m2 - hh;
    float ll = (float)(__bf16)r1;
    float r2 = r1 - ll;
    uh[c] = bfbits(hh); uh[128 + c] = bfbits(ll); uh[256 + c] = bfbits(r2);
}

__global__ __launch_bounds__(256) void t0_fillA_kernel(
        const float* __restrict__ u, const float* __restrict__ bnb,
        float4* __restrict__ out0) {
    int i = blockIdx.x * 256 + threadIdx.x;        // 589824 quads
    int c = ((i * 4) / HW) % COUT;
    float bb = bnb[c];
    out0[i] = make_float4(bb, bb, bb, bb);
}

// t=0 fill B: m2 planes buffer 0 (16-ch-blocked) + syn2 (fragment layout).
__global__ __launch_bounds__(256) void t0_fillB_kernel(
        const float* __restrict__ u,
        u16* __restrict__ m2, float4* __restrict__ syn2) {
    int i = blockIdx.x * 256 + threadIdx.x;        // 589824
    const u16* uh = (const u16*)(u + 128);
    int pxg = i >> 2;
    int cg = (pxg / HW) & 7;
    int c0 = cg * 16 + (i & 3) * 4;
    *(uint2*)(m2 + (size_t)i * 4)             = *(const uint2*)(uh + c0);
    *(uint2*)(m2 + M2PL + (size_t)i * 4)      = *(const uint2*)(uh + 128 + c0);
    *(uint2*)(m2 + 2 * M2PL + (size_t)i * 4)  = *(const uint2*)(uh + 256 + c0);
    int csy = ((i >> 9) & 7) * 16 + (i & 15);
    float s2 = u[csy];
    syn2[i] = make_float4(s2, s2, s2, s2);
}

// ---------------------------------------------------------------------------
// MFMA conv + fused LSTM. Block: 4 waves, wave = 1 nt, M=128 px (8x16 tile).
// Grid 1152: bx = ntq*144 + mt*8 + b -> XCD = b.
#define LDSROW(P, r, kw) (*(const bf16x8*)&alds[P][(((r) * 18) + m16 + (kw)) * 40 + kg * 8])
__global__ __launch_bounds__(256, 3) void conv_lstm_fused(
        const u16* __restrict__ spk1h,
        const u16* __restrict__ m2rd,      // base of 3 contiguous planes
        const u16* __restrict__ wt,
        const float* __restrict__ bias, const float* __restrict__ p_th2,
        float* __restrict__ syn2,
        u16* __restrict__ m2wr,            // base of 3 contiguous planes
        u16* __restrict__ spk2h, int* __restrict__ cnt) {
    __shared__ __align__(16) u16 alds[3][7200];    // 43.2 KB; reused as f32 glds

    const int bx  = blockIdx.x;
    const int ntq = bx / 144;
    const int rm  = bx - ntq * 144;
    const int mt  = rm >> 3;
    const int b   = rm & 7;
    const int mt3 = mt / 3;
    const int h0 = mt3 * 8, w0 = (mt - mt3 * 3) * 16;

    const int tid = threadIdx.x;
    const int wn  = tid >> 6;
    const int lane = tid & 63;
    const int m16 = lane & 15;
    const int kg  = lane >> 4;
    const int nt = ntq * 4 + wn;

    f32x4 acc[8];
#pragma unroll
    for (int mf = 0; mf < 8; ++mf) acc[mf] = (f32x4){0.f, 0.f, 0.f, 0.f};

    // ---- hoisted mem2 staging indices ----
    int ldsM[9], srcM[9];
#pragma unroll
    for (int j = 0; j < 9; ++j) {
        int i = tid + j * 256;
        int pl = i / 720;
        int r = i - pl * 720;
        int px = r >> 2, qt = r & 3;
        int rr = px / 18, cc2 = px - rr * 18;
        int gh = h0 - 1 + rr, gw = w0 - 1 + cc2;
        ldsM[j] = (i < 2160) ? (pl * 7200 + px * 40 + qt * 8) : -1;
        bool ok = (i < 2160) && ((unsigned)gh < 48u) && ((unsigned)gw < 48u);
        srcM[j] = ok ? (pl * M2PL + ((b * 8 + (qt >> 1)) * HW + gh * 48 + gw) * 16
                        + (qt & 1) * 8) : -1;
    }

    // ---- binary staging: ck 0,1 -> planes 0,1 (one shot) ----
    {
        uint4 stB[6]; int ldsB[6];
#pragma unroll
        for (int j = 0; j < 6; ++j) {
            int i = tid + j * 256;
            int ckb = i / 720;
            int r = i - ckb * 720;
            int px = r >> 2, qt = r & 3;
            int rr = px / 18, cc2 = px - rr * 18;
            int gh = h0 - 1 + rr, gw = w0 - 1 + cc2;
            ldsB[j] = (i < 1440) ? (ckb * 7200 + px * 40 + qt * 8) : -1;
            uint4 v = make_uint4(0u, 0u, 0u, 0u);
            if (i < 1440 && (unsigned)gh < 48u && (unsigned)gw < 48u)
                v = *(const uint4*)(spk1h
                    + ((size_t)(b * 4 + ckb * 2 + (qt >> 1)) * HW + gh * 48 + gw) * 16
                    + (qt & 1) * 8);
            stB[j] = v;
        }
#pragma unroll
        for (int j = 0; j < 6; ++j)
            if (ldsB[j] >= 0) *(uint4*)&alds[0][ldsB[j]] = stB[j];
    }
    __syncthreads();

    uint4 stM[9];
#define LOADM(ck_)                                                           \
    {                                                                        \
        const int add = ((ck_) - 2) * (2 * HW * 16);                         \
        _Pragma("unroll")                                                    \
        for (int j = 0; j < 9; ++j) {                                        \
            uint4 v = make_uint4(0u, 0u, 0u, 0u);                            \
            if (srcM[j] >= 0) v = *(const uint4*)(m2rd + srcM[j] + add);     \
            stM[j] = v;                                                      \
        }                                                                    \
    }
#define WRITEM                                                               \
    {                                                                        \
        _Pragma("unroll")                                                    \
        for (int j = 0; j < 9; ++j)                                          \
            if (ldsM[j] >= 0) *(uint4*)&alds[0][ldsM[j]] = stM[j];           \
    }

    LOADM(2);                                      // in flight under binary compute

    // ---- binary compute (3-term), planes 0,1 ----
    for (int ckb = 0; ckb < 2; ++ckb) {
#pragma unroll
        for (int kw = 0; kw < 3; ++kw) {
            bf16x8 B0[3], B1[3], B2[3];
#pragma unroll
            for (int kh = 0; kh < 3; ++kh) {
                const size_t bo = ((size_t)(nt * 6 + ckb) * 9 + kh * 3 + kw) * 512 + lane * 8;
                B0[kh] = *(const bf16x8*)(wt + bo);
                B1[kh] = *(const bf16x8*)(wt + WTPL + bo);
                B2[kh] = *(const bf16x8*)(wt + 2 * WTPL + bo);
            }
            bf16x8 aw[3];
            aw[0] = LDSROW(ckb, 0, kw);
            aw[1] = LDSROW(ckb, 1, kw);
#pragma unroll
            for (int mf = 0; mf < 8; ++mf) {
                aw[(mf + 2) % 3] = LDSROW(ckb, mf + 2, kw);
#pragma unroll
                for (int kh = 0; kh < 3; ++kh) {
                    const bf16x8 A = aw[(mf + kh) % 3];
                    acc[mf] = MFMA(A, B0[kh], acc[mf]);
                    acc[mf] = MFMA(A, B1[kh], acc[mf]);
                    acc[mf] = MFMA(A, B2[kh], acc[mf]);
                }
            }
        }
    }

    // ---- mem2 chunks (6-term), pipelined staging ----
    for (int ck = 2; ck < 6; ++ck) {
        __syncthreads();
        WRITEM;
        __syncthreads();
        if (ck < 5) LOADM(ck + 1);
#pragma unroll
        for (int kw = 0; kw < 3; ++kw) {
            bf16x8 B0[3], B1[3], B2[3];
#pragma unroll
            for (int kh = 0; kh < 3; ++kh) {
                const size_t bo = ((size_t)(nt * 6 + ck) * 9 + kh * 3 + kw) * 512 + lane * 8;
                B0[kh] = *(const bf16x8*)(wt + bo);
                B1[kh] = *(const bf16x8*)(wt + WTPL + bo);
                B2[kh] = *(const bf16x8*)(wt + 2 * WTPL + bo);
            }
            bf16x8 a0[3], a1[3], a2[3];
            a0[0] = LDSROW(0, 0, kw); a0[1] = LDSROW(0, 1, kw);
            a1[0] = LDSROW(1, 0, kw); a1[1] = LDSROW(1, 1, kw);
            a2[0] = LDSROW(2, 0, kw); a2[1] = LDSROW(2, 1, kw);
#pragma unroll
            for (int mf = 0; mf < 8; ++mf) {
                const int sn = (mf + 2) % 3;
                a0[sn] = LDSROW(0, mf + 2, kw);
                a1[sn] = LDSROW(1, mf + 2, kw);
                a2[sn] = LDSROW(2, mf + 2, kw);
#pragma unroll
                for (int kh = 0; kh < 3; ++kh) {
                    const int s = (mf + kh) % 3;
                    acc[mf] = MFMA(a0[s], B0[kh], acc[mf]);   // h  * wh
                    acc[mf] = MFMA(a0[s], B1[kh], acc[mf]);   // h  * wl
                    acc[mf] = MFMA(a0[s], B2[kh], acc[mf]);   // h  * wl2
                    acc[mf] = MFMA(a1[s], B0[kh], acc[mf]);   // l  * wh
                    acc[mf] = MFMA(a1[s], B1[kh], acc[mf]);   // l  * wl
                    acc[mf] = MFMA(a2[s], B0[kh], acc[mf]);   // l2 * wh
                    // l2*wl (~2^-27 rel) dropped — same class as the already-
                    // dropped l*wl2; error magnitude unchanged.
                }
            }
        }
    }

    // ---- gate exchange through LDS, then fused LSTM ----
    __syncthreads();
    {
        float* glds = (float*)alds;
#pragma unroll
        for (int mf = 0; mf < 8; ++mf)
            *(f32x4*)(glds + (wn * 8 + mf) * 256 + lane * 4) = acc[mf];
    }
    __syncthreads();
    {
#pragma clang fp contract(off)
        const float* glds = (const float*)alds;
        const int c = ntq * 16 + m16;
        const float th2 = p_th2[0];
        const float b0 = bias[c],       b1 = bias[128 + c];
        const float b2 = bias[256 + c], b3 = bias[384 + c];
        int sc = 0;
#pragma unroll
        for (int q = 0; q < 2; ++q) {
            const int mfq = wn * 2 + q;
            const f32x4 vI = *(const f32x4*)(glds + (0 * 8 + mfq) * 256 + lane * 4);
            const f32x4 vF = *(const f32x4*)(glds + (1 * 8 + mfq) * 256 + lane * 4);
            const f32x4 vG = *(const f32x4*)(glds + (2 * 8 + mfq) * 256 + lane * 4);
            const f32x4 vO = *(const f32x4*)(glds + (3 * 8 + mfq) * 256 + lane * 4);
            const size_t sidx = ((size_t)(((b * 18 + mt) * 8 + ntq) * 8 + mfq) * 64 + lane) * 4;
            const f32x4 s2v = *(const f32x4*)(syn2 + sidx);
            const int h = h0 + mfq;
            const size_t pixb = ((size_t)(b * 8 + ntq) * HW + h * 48 + w0 + kg * 4) * 16 + m16;
            f32x4 s2o;
#pragma unroll
            for (int j = 0; j < 4; ++j) {
                float gi = vI[j] + b0, gf = vF[j] + b1;
                float gg = vG[j] + b2, go = vO[j] + b3;
                float si = 1.0f / (1.0f + expf(-gi));
                float sf = 1.0f / (1.0f + expf(-gf));
                float so = 1.0f / (1.0f + expf(-go));
                float tg = tanhf(gg);
                float s2 = sf * s2v[j] + si * tg;
                float m2 = so * tanhf(s2);
                s2o[j] = s2;
                float hh = (float)(__bf16)m2;
                float r1 = m2 - hh;
                float ll = (float)(__bf16)r1;
                float r2 = r1 - ll;
                const size_t pix = pixb + (size_t)j * 16;
                m2wr[pix]             = bfbits(hh);
                m2wr[M2PL + pix]      = bfbits(ll);
                m2wr[2 * M2PL + pix]  = bfbits(r2);
                bool sp = (m2 - th2) > 0.0f;
                spk2h[pix] = sp ? 0x3F80u : 0u;
                sc += sp ? 1 : 0;
            }
            *(f32x4*)(syn2 + sidx) = s2o;
        }
        sc += __shfl_xor(sc, 16);
        sc += __shfl_xor(sc, 32);
        if (lane < 16) atomicAdd(&cnt[ntq * 16 + lane], sc);
    }
#undef LOADM
#undef WRITEM
}

// ---------------------------------------------------------------------------
// BN of binary spikes; spk2h is [B][8][HW][16].
__global__ __launch_bounds__(256) void bn_step_kernel(
        const u16* __restrict__ spk2h, const int* __restrict__ cnt,
        const float* __restrict__ gamma, const float* __restrict__ bnb,
        float4* __restrict__ out) {
#pragma clang fp contract(off)
    int i = blockIdx.x * 256 + threadIdx.x;        // 589824 quads (ch-major out)
    int e = i * 4;
    int tmp = e / HW;                               // b*128 + c
    int bb = tmp >> 7, c = tmp & 127;
    int hw0 = e - tmp * HW;
    const u16* sp = spk2h + ((size_t)(bb * 8 + (c >> 4)) * HW + hw0) * 16 + (c & 15);
    float mu  = (float)cnt[c] / (float)NPIX;
    float var = mu - mu * mu;
    float rs  = rsqrtf(var + 1e-5f);
    float g = gamma[c], bv = bnb[c];
    float s0 = bff(sp[0]), s1 = bff(sp[16]), s2 = bff(sp[32]), s3 = bff(sp[48]);
    out[i] = make_float4(g * (s0 - mu) * rs + bv, g * (s1 - mu) * rs + bv,
                         g * (s2 - mu) * rs + bv, g * (s3 - mu) * rs + bv);
}

// ---------------------------------------------------------------------------
extern "C" void kernel_launch(void* const* d_in, const int* in_sizes, int n_in,
                              void* d_out, int out_size, void* d_ws, size_t ws_size,
                              hipStream_t stream) {
    const float* x       = (const float*)d_in[0];
    const float* p_alpha = (const float*)d_in[1];
    const float* p_beta  = (const float*)d_in[2];
    const float* p_th1   = (const float*)d_in[3];
    const float* p_th2   = (const float*)d_in[4];
    const float* w_conv  = (const float*)d_in[5];
    const float* b_conv  = (const float*)d_in[6];
    const float* gamma   = (const float*)d_in[7];
    const float* bn_beta = (const float*)d_in[8];
    float* out = (float*)d_out;

    float* wsf   = (float*)d_ws;
    float* syn_e = wsf + OFF_SYNE;
    float* syn_i = wsf + OFF_SYNI;
    u16*   spk1h = (u16*)(wsf + OFF_SPK1H);
    int*   cnt   = (int*)(wsf + OFF_CNT);
    float* syn2  = wsf + OFF_SYN2;
    u16*   spk2h = (u16*)(wsf + OFF_SPK2H);
    u16*   m2buf[2] = {(u16*)(wsf + OFF_M2H0), (u16*)(wsf + OFF_M2H1)};
    u16*   wt    = (u16*)(wsf + OFF_WT);
    float* u     = wsf + OFF_U;

    zero_ws_kernel<<<ZERO_W / 256, 256, 0, stream>>>(wsf, ZERO_W);
    wt_transform_kernel<<<432, 256, 0, stream>>>(w_conv, wt);

    // ---- t = 0 (algebraic) ----
    alpha_step_kernel<<<1152, 256, 0, stream>>>(
        (const float4*)x, p_alpha, p_beta, p_th1,
        (float4*)syn_e, (float4*)syn_i, spk1h);
    t0_u_kernel<<<1, COUT, 0, stream>>>(b_conv, u);
    t0_fillA_kernel<<<2304, 256, 0, stream>>>(u, bn_beta, (float4*)out);
    t0_fillB_kernel<<<2304, 256, 0, stream>>>(u, m2buf[0], (float4*)syn2);

    // ---- t = 1..3 ----
    for (int t = 1; t < T_; ++t) {
        const int rd = (t - 1) & 1, wr = t & 1;
        alpha_step_kernel<<<1152, 256, 0, stream>>>(
            (const float4*)(x + (size_t)t * 1179648), p_alpha, p_beta, p_th1,
            (float4*)syn_e, (float4*)syn_i, spk1h);
        conv_lstm_fused<<<1152, 256, 0, stream>>>(
            spk1h, m2buf[rd], wt, b_conv, p_th2,
            syn2, m2buf[wr], spk2h, cnt + t * COUT);
        bn_step_kernel<<<2304, 256, 0, stream>>>(
            spk2h, cnt + t * COUT, gamma, bn_beta,
            (float4*)(out + (size_t)t * 2359296));
    }
}